// Round 7
// baseline (103.435 us; speedup 1.0000x reference)
//
#include <hip/hip_runtime.h>
#include <hip/hip_fp16.h>

// Fused: embedding gather -> masked mean -> ReLU -> linear(20x50)+bias
//   VOCAB=100000, DIM=50, B=4096, L=512, OUT=20
// R5 post-mortem: gather pinned at ~4.3 TB/s on the L2-miss path (95MB
// compulsory fetch because each XCD pulls the whole 12.8MB table through 4MB
// L2). R6/R7: shard the table 8x1.6MB, pin shard s to XCD s via blockIdx%8,
// bin tokens by shard per sample -> gathers become L2 hits.
// R7: + runtime fallback to the proven R5 monolithic path if ws_size is too
// small for the sharded layout (ws_size is call-invariant -> capture-safe).

#define LMAX    512
#define DIMV    50
#define OUTV    20
#define VOCABSZ 100000
#define RSTRIDE 64          // padded f16 row stride (128 B)
#define NSHARD  8
#define SHROWS  12500       // rows per shard (12500*128B = 1.6 MB, fits 4MB L2)
#define BINCAP  576         // per-sample binned capacity (512 + 8 shards * 7 pad)
#define TABBLKS 3126        // ceil((VOCABSZ+1)*8 / 256)

struct __align__(16) H8 { __half2 h[4]; };   // 8 halves = 16 B

// ws layout (poisoned 0xAA each call; everything read is written first):
//   tab      @ 0     : half  [(VOCABSZ+1)*64]   12.80 MB
//   gbin     @ 16 MB : int   [B][BINCAP]         9.44 MB
//   bofs     @ 28 MB : int2  [B][NSHARD]         0.26 MB
//   partials @ 29 MB : float [B][NSHARD*64]      8.39 MB
#define OFF_GBIN  (16u << 20)
#define OFF_BOFS  (28u << 20)
#define OFF_PART  (29u << 20)

__device__ inline void accum(float4& a0, float4& a1, const H8& h) {
    float2 f0 = __half22float2(h.h[0]);
    float2 f1 = __half22float2(h.h[1]);
    float2 f2 = __half22float2(h.h[2]);
    float2 f3 = __half22float2(h.h[3]);
    a0.x += f0.x; a0.y += f0.y; a0.z += f1.x; a0.w += f1.y;
    a1.x += f2.x; a1.y += f2.y; a1.z += f3.x; a1.w += f3.y;
}

// ---- Kernel 1: table build (blocks < TABBLKS) || token binning (one block/sample) ----
// Launch with grid = TABBLKS (table only, fallback path) or TABBLKS + B (sharded).
__global__ __launch_bounds__(256) void prep(
    const float* __restrict__ emb, const int* __restrict__ x,
    const int* __restrict__ lengths, char* __restrict__ ws)
{
    const int tid = threadIdx.x;

    if (blockIdx.x < TABBLKS) {
        // f32 -> padded f16 table (+ zero row at index VOCABSZ)
        __half* tab = (__half*)ws;
        const int t = blockIdx.x * 256 + tid;
        const int r = t >> 3, q = t & 7;
        if (r > VOCABSZ) return;
        float v[8] = {0.f,0.f,0.f,0.f,0.f,0.f,0.f,0.f};
        if (r < VOCABSZ) {
            const float* src = emb + r * DIMV + q * 8;
            if (q < 6) {
                #pragma unroll
                for (int j = 0; j < 8; j += 2) {
                    float2 a = *reinterpret_cast<const float2*>(src + j);
                    v[j] = a.x; v[j + 1] = a.y;
                }
            } else if (q == 6) {                 // dims 48,49
                float2 a = *reinterpret_cast<const float2*>(src);
                v[0] = a.x; v[1] = a.y;
            }
        }
        H8 h;
        h.h[0] = __floats2half2_rn(v[0], v[1]);
        h.h[1] = __floats2half2_rn(v[2], v[3]);
        h.h[2] = __floats2half2_rn(v[4], v[5]);
        h.h[3] = __floats2half2_rn(v[6], v[7]);
        *reinterpret_cast<H8*>(tab + r * RSTRIDE + q * 8) = h;
        return;
    }

    // ---- binning: group sample b's tokens by shard, pad segments to x8 ----
    const int b = blockIdx.x - TABBLKS;
    int*  gbin = (int*)(ws + OFF_GBIN);
    int2* bofs = (int2*)(ws + OFF_BOFS);

    __shared__ int sidx[LMAX];
    __shared__ int sbin[BINCAP];
    __shared__ int cnt[NSHARD], pcnt[NSHARD], base[NSHARD], pos[NSHARD];

    if (tid < NSHARD) { cnt[tid] = 0; pos[tid] = 0; }
    __syncthreads();

    const int len = lengths[b];
    #pragma unroll
    for (int i = tid; i < LMAX; i += 256) {
        const int v = x[b * LMAX + i];
        sidx[i] = v;
        if (i < len) atomicAdd(&cnt[v / SHROWS], 1);
    }
    __syncthreads();
    if (tid == 0) {
        int run = 0;
        #pragma unroll
        for (int s = 0; s < NSHARD; ++s) {
            base[s] = run;
            pcnt[s] = (cnt[s] + 7) & ~7;         // pad to 8-token chunks
            run += pcnt[s];
        }
    }
    __syncthreads();
    #pragma unroll
    for (int i = tid; i < LMAX; i += 256) {
        if (i < len) {
            const int v = sidx[i];
            const int s = v / SHROWS;
            const int p = atomicAdd(&pos[s], 1); // order within shard irrelevant (sum)
            sbin[base[s] + p] = v;
        }
    }
    __syncthreads();
    if (tid < 64) {                              // sentinel-pad each segment
        const int s = tid >> 3, k = tid & 7;
        if (cnt[s] + k < pcnt[s]) sbin[base[s] + cnt[s] + k] = VOCABSZ;
    }
    __syncthreads();
    const int total = base[NSHARD - 1] + pcnt[NSHARD - 1];
    for (int j = tid; j < total; j += 256) gbin[b * BINCAP + j] = sbin[j];
    if (tid < NSHARD) bofs[b * NSHARD + tid] = make_int2(base[tid], pcnt[tid]);
}

// ---- Kernel 2: XCD-affine sharded gather. shard = blockIdx%8, wave = sample. ----
__global__ __launch_bounds__(256) void shard_gather(char* __restrict__ ws)
{
    const __half* tab  = (const __half*)ws;
    const int*    gbin = (const int*)(ws + OFF_GBIN);
    const int2*   bofs = (const int2*)(ws + OFF_BOFS);
    float*        part = (float*)(ws + OFF_PART);

    const int s    = blockIdx.x & 7;             // XCD-affine shard
    const int grp  = blockIdx.x >> 3;
    const int tid  = threadIdx.x;
    const int wave = tid >> 6, lane = tid & 63;
    const int rg   = lane >> 3, cl = lane & 7;   // 8 lanes/row, 8 rows/chunk
    const int b    = grp * 4 + wave;

    __shared__ int slab[4][520];

    const int2 of = bofs[b * NSHARD + s];        // .x = base, .y = padded count
    const int* seg = gbin + b * BINCAP + of.x;
    for (int i = lane; i < of.y; i += 64) slab[wave][i] = seg[i];
    __syncthreads();

    const __half* tabc = tab + cl * 8;
    const int nch = of.y >> 3;
    float4 a0 = {0.f,0.f,0.f,0.f}, a1 = {0.f,0.f,0.f,0.f};
    int c = 0;
    for (; c + 3 < nch; c += 4) {                // 4 x 1KB loads in flight
        const int i0 = slab[wave][(c    ) * 8 + rg];
        const int i1 = slab[wave][(c + 1) * 8 + rg];
        const int i2 = slab[wave][(c + 2) * 8 + rg];
        const int i3 = slab[wave][(c + 3) * 8 + rg];
        H8 h0 = *reinterpret_cast<const H8*>(tabc + (i0 << 6));
        H8 h1 = *reinterpret_cast<const H8*>(tabc + (i1 << 6));
        H8 h2 = *reinterpret_cast<const H8*>(tabc + (i2 << 6));
        H8 h3 = *reinterpret_cast<const H8*>(tabc + (i3 << 6));
        accum(a0, a1, h0); accum(a0, a1, h1);
        accum(a0, a1, h2); accum(a0, a1, h3);
    }
    for (; c < nch; ++c) {
        const int i0 = slab[wave][c * 8 + rg];
        H8 h0 = *reinterpret_cast<const H8*>(tabc + (i0 << 6));
        accum(a0, a1, h0);
    }

    // Sum the 8 row-groups (butterfly over lane bits 3,4,5); lanes 0..7 hold row.
    #pragma unroll
    for (int m = 8; m <= 32; m <<= 1) {
        a0.x += __shfl_xor(a0.x, m); a0.y += __shfl_xor(a0.y, m);
        a0.z += __shfl_xor(a0.z, m); a0.w += __shfl_xor(a0.w, m);
        a1.x += __shfl_xor(a1.x, m); a1.y += __shfl_xor(a1.y, m);
        a1.z += __shfl_xor(a1.z, m); a1.w += __shfl_xor(a1.w, m);
    }
    if (lane < 8) {                              // lane L holds dims 8L..8L+7
        float* p = part + b * (NSHARD * 64) + s * 64 + lane * 8;
        *reinterpret_cast<float4*>(p)     = a0;
        *reinterpret_cast<float4*>(p + 4) = a1;
    }
}

// ---- Kernel 3: reduce 8 partials -> mean -> ReLU -> 20x50 matvec ----
__global__ __launch_bounds__(256) void finalize(
    const int* __restrict__ lengths, const float* __restrict__ W,
    const float* __restrict__ bias, const char* __restrict__ ws,
    float* __restrict__ out)
{
    const float* part = (const float*)(ws + OFF_PART);
    const int tid = threadIdx.x, wave = tid >> 6, lane = tid & 63;
    const int b = blockIdx.x * 4 + wave;

    __shared__ float srep[4][64];

    float v = 0.f;
    #pragma unroll
    for (int s = 0; s < NSHARD; ++s)
        v += part[b * (NSHARD * 64) + s * 64 + lane];   // coalesced per s
    const float inv = 1.0f / (float)lengths[b];
    srep[wave][lane] = fmaxf(v * inv, 0.f);              // dims 50..63 are 0
    __syncthreads();

    if (lane < OUTV) {
        float acc = bias[lane];
        const float* wr = W + lane * DIMV;
        #pragma unroll
        for (int d = 0; d < DIMV; ++d) acc += srep[wave][d] * wr[d];
        out[b * OUTV + lane] = acc;
    }
}

// ---- Fallback (R5 path, proven 97.7us): monolithic gather on full table ----
__global__ __launch_bounds__(256) void fused_gather(
    const int*    __restrict__ x,
    const int*    __restrict__ lengths,
    const __half* __restrict__ tab,
    const float*  __restrict__ W,
    const float*  __restrict__ bias,
    float*        __restrict__ out)
{
    const int b    = blockIdx.x;
    const int tid  = threadIdx.x;
    const int wave = tid >> 6;
    const int lane = tid & 63;
    const int rg   = lane >> 3;
    const int cl   = lane & 7;

    __shared__ int   sidx[LMAX];
    __shared__ float sacc[4][64];
    __shared__ float srep[DIMV];

    const int len = lengths[b];
    const int xbase = b * LMAX;
    #pragma unroll
    for (int i = 0; i < LMAX; i += 256) {
        const int ii = i + tid;
        const int v  = x[xbase + ii];
        sidx[ii] = (ii < len) ? v : VOCABSZ;
    }
    __syncthreads();

    const __half* tabc = tab + cl * 8;
    const int nchunk = (len + 7) >> 3;
    float4 a0 = {0.f,0.f,0.f,0.f}, a1 = {0.f,0.f,0.f,0.f};

    int c = wave;
    for (; c + 28 < nchunk; c += 32) {
        int i0 = sidx[(c     ) * 8 + rg];
        int i1 = sidx[(c +  4) * 8 + rg];
        int i2 = sidx[(c +  8) * 8 + rg];
        int i3 = sidx[(c + 12) * 8 + rg];
        int i4 = sidx[(c + 16) * 8 + rg];
        int i5 = sidx[(c + 20) * 8 + rg];
        int i6 = sidx[(c + 24) * 8 + rg];
        int i7 = sidx[(c + 28) * 8 + rg];
        H8 h0 = *reinterpret_cast<const H8*>(tabc + (i0 << 6));
        H8 h1 = *reinterpret_cast<const H8*>(tabc + (i1 << 6));
        H8 h2 = *reinterpret_cast<const H8*>(tabc + (i2 << 6));
        H8 h3 = *reinterpret_cast<const H8*>(tabc + (i3 << 6));
        H8 h4 = *reinterpret_cast<const H8*>(tabc + (i4 << 6));
        H8 h5 = *reinterpret_cast<const H8*>(tabc + (i5 << 6));
        H8 h6 = *reinterpret_cast<const H8*>(tabc + (i6 << 6));
        H8 h7 = *reinterpret_cast<const H8*>(tabc + (i7 << 6));
        accum(a0, a1, h0); accum(a0, a1, h1); accum(a0, a1, h2); accum(a0, a1, h3);
        accum(a0, a1, h4); accum(a0, a1, h5); accum(a0, a1, h6); accum(a0, a1, h7);
    }
    for (; c < nchunk; c += 4) {
        int i0 = sidx[c * 8 + rg];
        H8 h0 = *reinterpret_cast<const H8*>(tabc + (i0 << 6));
        accum(a0, a1, h0);
    }

    #pragma unroll
    for (int m = 8; m <= 32; m <<= 1) {
        a0.x += __shfl_xor(a0.x, m); a0.y += __shfl_xor(a0.y, m);
        a0.z += __shfl_xor(a0.z, m); a0.w += __shfl_xor(a0.w, m);
        a1.x += __shfl_xor(a1.x, m); a1.y += __shfl_xor(a1.y, m);
        a1.z += __shfl_xor(a1.z, m); a1.w += __shfl_xor(a1.w, m);
    }
    if (lane < 8) {
        *reinterpret_cast<float4*>(&sacc[wave][lane * 8])     = a0;
        *reinterpret_cast<float4*>(&sacc[wave][lane * 8 + 4]) = a1;
    }
    __syncthreads();

    if (tid < DIMV) {
        float s = sacc[0][tid] + sacc[1][tid] + sacc[2][tid] + sacc[3][tid];
        srep[tid] = fmaxf(s / (float)len, 0.f);
    }
    __syncthreads();

    if (tid < OUTV) {
        float s = bias[tid];
        const float* wr = W + tid * DIMV;
        #pragma unroll
        for (int d = 0; d < DIMV; ++d) s += srep[d] * wr[d];
        out[b * OUTV + tid] = s;
    }
}

extern "C" void kernel_launch(void* const* d_in, const int* in_sizes, int n_in,
                              void* d_out, int out_size, void* d_ws, size_t ws_size,
                              hipStream_t stream) {
    const int*   x       = (const int*)  d_in[0];
    const int*   lengths = (const int*)  d_in[1];
    const float* emb     = (const float*)d_in[2];
    const float* W       = (const float*)d_in[3];
    const float* bias    = (const float*)d_in[4];
    float* out = (float*)d_out;
    char*  ws  = (char*)d_ws;

    const int B = in_sizes[1];                   // 4096
    const size_t NEED = (size_t)OFF_PART + (size_t)B * NSHARD * 64 * sizeof(float);

    if (ws_size >= NEED) {
        // Sharded, XCD-affine path (~37.4 MB ws).
        prep<<<TABBLKS + B, 256, 0, stream>>>(emb, x, lengths, ws);
        shard_gather<<<(B / 4) * NSHARD, 256, 0, stream>>>(ws);
        finalize<<<B / 4, 256, 0, stream>>>(lengths, W, bias, ws, out);
    } else {
        // Fallback: R5 monolithic path (12.8 MB ws).
        prep<<<TABBLKS, 256, 0, stream>>>(emb, x, lengths, ws);
        fused_gather<<<B, 256, 0, stream>>>(x, lengths, (const __half*)ws, W, bias, out);
    }
}